// Round 1
// baseline (362.522 us; speedup 1.0000x reference)
//
#include <hip/hip_runtime.h>
#include <hip/hip_bf16.h>

#define N_Q   16384
#define MCTX  4096
#define DSIN  256
#define YDIM  7
#define PDIM  256   // SPROJ

typedef __attribute__((ext_vector_type(8))) short s16x8;   // 8 bf16 (4 VGPRs)
typedef __attribute__((ext_vector_type(4))) float f32x4;   // MFMA C/D frag
typedef unsigned short u16;

static __device__ __forceinline__ u16 f2bf(float f) {
    union { float f; unsigned u; } v; v.f = f;
    unsigned r = v.u + 0x7fffu + ((v.u >> 16) & 1u);  // RNE
    return (u16)(r >> 16);
}
static __device__ __forceinline__ float bf2f(u16 h) {
    union { unsigned u; float f; } v; v.u = ((unsigned)h) << 16;
    return v.f;
}
static __device__ __forceinline__ f32x4 mfma16(s16x8 a, s16x8 b, f32x4 c) {
    return __builtin_amdgcn_mfma_f32_16x16x32_bf16(a, b, c, 0, 0, 0);
}

// ---------------- K0: Wq transpose + hi/lo bf16 split ----------------
// WtH/WtL: [PDIM][DSIN] (n-major) so B-frags read contiguous k runs.
__global__ void k_wt(const float* __restrict__ Wq, u16* __restrict__ WtH,
                     u16* __restrict__ WtL) {
    int n = blockIdx.x;   // 0..PDIM-1
    int k = threadIdx.x;  // 0..DSIN-1
    float w = Wq[(size_t)k * PDIM + n];
    u16 h = f2bf(w);
    WtH[(size_t)n * DSIN + k] = h;
    WtL[(size_t)n * DSIN + k] = f2bf(w - bf2f(h));
}

// ---------------- K2: YK (scaled by 1/16) and YV transposed ----------------
__global__ void k_ykv(const float* __restrict__ y, const float* __restrict__ Wk,
                      const float* __restrict__ Wv, u16* __restrict__ YK,
                      u16* __restrict__ YVt) {
    int m = blockIdx.x;   // key
    int p = threadIdx.x;  // proj
    float acck = 0.f, accv = 0.f;
#pragma unroll
    for (int j = 0; j < YDIM; ++j) {
        float yj = y[(size_t)m * YDIM + j];
        acck += yj * Wk[(size_t)j * PDIM + p];
        accv += yj * Wv[(size_t)j * PDIM + p];
    }
    YK[(size_t)m * PDIM + p]  = f2bf(acck * 0.0625f);  // fold 1/sqrt(256)
    YVt[(size_t)p * MCTX + m] = f2bf(accv);
}

// ---------------- K1: XQ = x @ Wq via split hi/lo bf16 MFMA ----------------
// A-frag layout: m = lane&15, k = (lane>>4)*8 + j.  B-frag: n = lane&15, same k.
__global__ __launch_bounds__(256, 2) void k_xq(const float* __restrict__ x,
                                               const u16* __restrict__ WtH,
                                               const u16* __restrict__ WtL,
                                               u16* __restrict__ XQ) {
    const int wave = threadIdx.x >> 6, lane = threadIdx.x & 63;
    const int quad = lane >> 4, m16 = lane & 15;
    const int rbase = blockIdx.x * 64 + wave * 16;

    s16x8 ah[8], al[8];
#pragma unroll
    for (int kf = 0; kf < 8; ++kf) {
        const float* px = x + (size_t)(rbase + m16) * DSIN + kf * 32 + quad * 8;
#pragma unroll
        for (int j = 0; j < 8; ++j) {
            float v = px[j];
            u16 h = f2bf(v);
            ah[kf][j] = (short)h;
            al[kf][j] = (short)f2bf(v - bf2f(h));
        }
    }
    f32x4 acc[16];
#pragma unroll
    for (int pt = 0; pt < 16; ++pt) acc[pt] = (f32x4){0.f, 0.f, 0.f, 0.f};

#pragma unroll
    for (int kf = 0; kf < 8; ++kf) {
#pragma unroll
        for (int pt = 0; pt < 16; ++pt) {
            size_t idx = (size_t)(pt * 16 + m16) * DSIN + kf * 32 + quad * 8;
            s16x8 bh = *(const s16x8*)(WtH + idx);
            s16x8 bl = *(const s16x8*)(WtL + idx);
            acc[pt] = mfma16(ah[kf], bh, acc[pt]);
            acc[pt] = mfma16(al[kf], bh, acc[pt]);
            acc[pt] = mfma16(ah[kf], bl, acc[pt]);
        }
    }
    // C/D layout: row = quad*4 + r, col = lane&15
#pragma unroll
    for (int pt = 0; pt < 16; ++pt)
#pragma unroll
        for (int r = 0; r < 4; ++r)
            XQ[(size_t)(rbase + quad * 4 + r) * PDIM + pt * 16 + m16] = f2bf(acc[pt][r]);
}

// ---------------- K3: fused attention (no-max online, dual path) ----------------
__global__ __launch_bounds__(256, 2) void k_attn(const u16* __restrict__ XQ,
                                                 const u16* __restrict__ YK,
                                                 const u16* __restrict__ YVt,
                                                 float* __restrict__ accE,
                                                 float* __restrict__ accR,
                                                 float* __restrict__ lsum,
                                                 float* __restrict__ rsum,
                                                 int msPerSplit) {
    __shared__ u16 Kt[32][DSIN + 8];     // keys x d, pad -> 2-way only
    __shared__ u16 Vt[PDIM][32 + 8];     // p x keys, pad -> 2-way only
    __shared__ float Sld[4][16][36];     // per-wave S tile, pad -> 2-way only

    const int tid = threadIdx.x;
    const int wave = tid >> 6, lane = tid & 63;
    const int quad = lane >> 4, m16 = lane & 15;
    const int split = blockIdx.y;
    const int qbase = blockIdx.x * 64 + wave * 16;

    // Q fragments (A-layout) for this wave's 16 rows, full d=256
    s16x8 qf[8];
#pragma unroll
    for (int kf = 0; kf < 8; ++kf)
        qf[kf] = *(const s16x8*)(XQ + (size_t)(qbase + m16) * DSIN + kf * 32 + quad * 8);

    f32x4 aE[16], aR[16];
#pragma unroll
    for (int pt = 0; pt < 16; ++pt) {
        aE[pt] = (f32x4){0.f, 0.f, 0.f, 0.f};
        aR[pt] = (f32x4){0.f, 0.f, 0.f, 0.f};
    }
    float lacc = 0.f, racc = 0.f;

    const int key_begin = split * msPerSplit;
    const int iters = msPerSplit >> 5;  // /32

    for (int it = 0; it < iters; ++it) {
        const int key0 = key_begin + it * 32;

        // stage K tile (32x256 bf16) and V^T tile (256x32 bf16)
#pragma unroll
        for (int c = 0; c < 4; ++c) {
            int idx = tid + c * 256;          // 0..1023
            int r = idx >> 5, cc = (idx & 31) * 8;
            *(s16x8*)(&Kt[r][cc]) = *(const s16x8*)(YK + (size_t)(key0 + r) * PDIM + cc);
        }
#pragma unroll
        for (int c = 0; c < 4; ++c) {
            int idx = tid + c * 256;
            int r = idx >> 2, cc = (idx & 3) * 8;
            *(s16x8*)(&Vt[r][cc]) = *(const s16x8*)(YVt + (size_t)r * MCTX + key0 + cc);
        }
        __syncthreads();

        // S = Q K^T (two 16-key n-tiles)
        f32x4 s0 = (f32x4){0.f, 0.f, 0.f, 0.f};
        f32x4 s1 = (f32x4){0.f, 0.f, 0.f, 0.f};
#pragma unroll
        for (int kf = 0; kf < 8; ++kf) {
            s16x8 b0 = *(const s16x8*)(&Kt[m16][kf * 32 + quad * 8]);
            s16x8 b1 = *(const s16x8*)(&Kt[16 + m16][kf * 32 + quad * 8]);
            s0 = mfma16(qf[kf], b0, s0);
            s1 = mfma16(qf[kf], b1, s1);
        }

        // C-layout -> LDS (wave-private; in-wave RAW ordered by lgkmcnt)
#pragma unroll
        for (int r = 0; r < 4; ++r) {
            Sld[wave][quad * 4 + r][m16]      = s0[r];
            Sld[wave][quad * 4 + r][16 + m16] = s1[r];
        }

        // A-layout read: row m16, keys quad*8..quad*8+7; exp + relu + row sums
        float le = 0.f, lr = 0.f;
        s16x8 pe, pr;
#pragma unroll
        for (int j = 0; j < 8; ++j) {
            float v = Sld[wave][m16][quad * 8 + j];
            float e = __expf(v);
            float rl = fmaxf(v, 0.f);
            le += e;
            lr += rl;
            pe[j] = (short)f2bf(e);
            pr[j] = (short)f2bf(rl);
        }
        le += __shfl_xor(le, 16); le += __shfl_xor(le, 32);
        lr += __shfl_xor(lr, 16); lr += __shfl_xor(lr, 32);
        lacc += le;
        racc += lr;

        // PV: both paths share each V B-fragment
#pragma unroll
        for (int pt = 0; pt < 16; ++pt) {
            s16x8 vb = *(const s16x8*)(&Vt[pt * 16 + m16][quad * 8]);
            aE[pt] = mfma16(pe, vb, aE[pt]);
            aR[pt] = mfma16(pr, vb, aR[pt]);
        }
        __syncthreads();
    }

    // write partials
    size_t obase = ((size_t)split * N_Q + qbase) * PDIM;
#pragma unroll
    for (int pt = 0; pt < 16; ++pt)
#pragma unroll
        for (int r = 0; r < 4; ++r) {
            size_t o = obase + (size_t)(quad * 4 + r) * PDIM + pt * 16 + m16;
            accE[o] = aE[pt][r];
            accR[o] = aR[pt][r];
        }
    if (lane < 16) {
        int row = split * N_Q + qbase + lane;
        lsum[row] = lacc;
        rsum[row] = racc;
    }
}

// ---------------- K4: combine splits + final normalization ----------------
__global__ void k_comb(const float* __restrict__ accE, const float* __restrict__ accR,
                       const float* __restrict__ lsum, const float* __restrict__ rsum,
                       float* __restrict__ out, int nsplit) {
    size_t idx = (size_t)blockIdx.x * 256 + threadIdx.x;
    int n = blockIdx.x;  // PDIM == blockDim == 256 -> one row per block
    float E = 0.f, R = 0.f, L = 0.f, Rs = 0.f;
    for (int s = 0; s < nsplit; ++s) {
        E += accE[(size_t)s * N_Q * PDIM + idx];
        R += accR[(size_t)s * N_Q * PDIM + idx];
    }
    for (int s = 0; s < nsplit; ++s) {
        L  += lsum[(size_t)s * N_Q + n];
        Rs += rsum[(size_t)s * N_Q + n];
    }
    out[idx] = (0.1f * R + E / L) / (1.f + 0.1f * Rs);
}

extern "C" void kernel_launch(void* const* d_in, const int* in_sizes, int n_in,
                              void* d_out, int out_size, void* d_ws, size_t ws_size,
                              hipStream_t stream) {
    const float* x  = (const float*)d_in[0];
    const float* y  = (const float*)d_in[1];
    const float* Wq = (const float*)d_in[2];
    const float* Wk = (const float*)d_in[3];
    const float* Wv = (const float*)d_in[4];
    float* out = (float*)d_out;

    char* ws = (char*)d_ws;
    size_t off = 0;
    auto take = [&](size_t bytes) -> char* {
        char* p = ws + off;
        off += (bytes + 255) & ~(size_t)255;
        return p;
    };
    u16* XQ  = (u16*)take((size_t)N_Q * PDIM * 2);
    u16* WtH = (u16*)take((size_t)PDIM * DSIN * 2);
    u16* WtL = (u16*)take((size_t)PDIM * DSIN * 2);
    u16* YK  = (u16*)take((size_t)MCTX * PDIM * 2);
    u16* YVt = (u16*)take((size_t)PDIM * MCTX * 2);

    size_t perSplit = (size_t)N_Q * PDIM * 4 * 2 + (size_t)N_Q * 4 * 2 + 1024;
    int nsplit = (ws_size >= off + 2 * perSplit + 4096) ? 2 : 1;

    float* accE = (float*)take((size_t)nsplit * N_Q * PDIM * 4);
    float* accR = (float*)take((size_t)nsplit * N_Q * PDIM * 4);
    float* lsum = (float*)take((size_t)nsplit * N_Q * 4);
    float* rsum = (float*)take((size_t)nsplit * N_Q * 4);

    hipLaunchKernelGGL(k_wt,   dim3(PDIM),        dim3(DSIN), 0, stream, Wq, WtH, WtL);
    hipLaunchKernelGGL(k_ykv,  dim3(MCTX),        dim3(PDIM), 0, stream, y, Wk, Wv, YK, YVt);
    hipLaunchKernelGGL(k_xq,   dim3(N_Q / 64),    dim3(256),  0, stream, x, WtH, WtL, XQ);
    hipLaunchKernelGGL(k_attn, dim3(N_Q / 64, nsplit), dim3(256), 0, stream,
                       XQ, YK, YVt, accE, accR, lsum, rsum, MCTX / nsplit);
    hipLaunchKernelGGL(k_comb, dim3(N_Q),         dim3(PDIM), 0, stream,
                       accE, accR, lsum, rsum, out, nsplit);
}

// Round 2
// 236.293 us; speedup vs baseline: 1.5342x; 1.5342x over previous
//
#include <hip/hip_runtime.h>
#include <hip/hip_bf16.h>

#define N_Q   16384
#define MCTX  4096
#define DSIN  256
#define YDIM  7
#define PDIM  256   // SPROJ
#define BK    32

typedef __attribute__((ext_vector_type(8))) short s16x8;   // 8 bf16 (4 VGPRs)
typedef __attribute__((ext_vector_type(4))) float f32x4;   // MFMA C/D frag
typedef unsigned short u16;

static __device__ __forceinline__ u16 f2bf(float f) {
    union { float f; unsigned u; } v; v.f = f;
    unsigned r = v.u + 0x7fffu + ((v.u >> 16) & 1u);  // RNE
    return (u16)(r >> 16);
}
static __device__ __forceinline__ float bf2f(u16 h) {
    union { unsigned u; float f; } v; v.u = ((unsigned)h) << 16;
    return v.f;
}
static __device__ __forceinline__ f32x4 mfma16(s16x8 a, s16x8 b, f32x4 c) {
    return __builtin_amdgcn_mfma_f32_16x16x32_bf16(a, b, c, 0, 0, 0);
}
// async 16B global->LDS DMA (dst = wave-uniform base + lane*16)
static __device__ __forceinline__ void gload_lds16(const u16* g, u16* l) {
    __builtin_amdgcn_global_load_lds(
        (const __attribute__((address_space(1))) unsigned int*)(g),
        (__attribute__((address_space(3))) unsigned int*)(l), 16, 0, 0);
}

// ---------------- K0: Wq transpose + hi/lo bf16 split ----------------
__global__ void k_wt(const float* __restrict__ Wq, u16* __restrict__ WtH,
                     u16* __restrict__ WtL) {
    int n = blockIdx.x;   // 0..PDIM-1
    int k = threadIdx.x;  // 0..DSIN-1
    float w = Wq[(size_t)k * PDIM + n];
    u16 h = f2bf(w);
    WtH[(size_t)n * DSIN + k] = h;
    WtL[(size_t)n * DSIN + k] = f2bf(w - bf2f(h));
}

// ---------------- K2: YK (scaled 1/16, row-major) + YVb (coalesced PV-frag layout) ----
// YVb[key>>5][p][key&31]: per-block contiguous 16KB; thread writes 64B contiguous.
__global__ void k_ykv(const float* __restrict__ y, const float* __restrict__ Wk,
                      const float* __restrict__ Wv, u16* __restrict__ YK,
                      u16* __restrict__ YVb) {
    int kb = blockIdx.x;   // key block (32 keys)
    int p  = threadIdx.x;  // proj
    float wk[YDIM], wv[YDIM];
#pragma unroll
    for (int j = 0; j < YDIM; ++j) {
        wk[j] = Wk[(size_t)j * PDIM + p];
        wv[j] = Wv[(size_t)j * PDIM + p];
    }
    u16 vbuf[32];
#pragma unroll
    for (int m = 0; m < 32; ++m) {
        int key = kb * 32 + m;
        float ak = 0.f, av = 0.f;
#pragma unroll
        for (int j = 0; j < YDIM; ++j) {
            float yy = y[(size_t)key * YDIM + j];
            ak += yy * wk[j];
            av += yy * wv[j];
        }
        YK[(size_t)key * PDIM + p] = f2bf(ak * 0.0625f);  // fold 1/sqrt(256)
        vbuf[m] = f2bf(av);
    }
    s16x8* dst = (s16x8*)(YVb + ((size_t)kb * PDIM + p) * 32);
#pragma unroll
    for (int c = 0; c < 4; ++c) dst[c] = ((s16x8*)vbuf)[c];
}

// ---------------- K1: XQ = x @ Wq, hi/lo split; x staged via swizzled LDS ----------------
__global__ __launch_bounds__(256, 1) void k_xq(const float* __restrict__ x,
                                               const u16* __restrict__ WtH,
                                               const u16* __restrict__ WtL,
                                               u16* __restrict__ XQ) {
    __shared__ u16 xH[64 * 256];  // XOR-swizzled 16B chunks: phys c = c ^ (row&7)
    __shared__ u16 xL[64 * 256];
    const int tid = threadIdx.x;
    const int rowg0 = blockIdx.x * 64;

    // stage x (coalesced float4) -> bf16 hi/lo in LDS
#pragma unroll
    for (int i = 0; i < 8; ++i) {
        int row = (tid >> 5) + i * 8;
        int c32 = tid & 31;                         // logical chunk (8 f32 cols / 8)
        const float* px = x + (size_t)(rowg0 + row) * DSIN + c32 * 8;
        float4 a = *(const float4*)px;
        float4 b = *(const float4*)(px + 4);
        float vals[8] = {a.x, a.y, a.z, a.w, b.x, b.y, b.z, b.w};
        s16x8 h, l;
#pragma unroll
        for (int j = 0; j < 8; ++j) {
            u16 hh = f2bf(vals[j]);
            h[j] = (short)hh;
            l[j] = (short)f2bf(vals[j] - bf2f(hh));
        }
        int pc = c32 ^ (row & 7);
        *(s16x8*)(xH + row * 256 + pc * 8) = h;
        *(s16x8*)(xL + row * 256 + pc * 8) = l;
    }
    __syncthreads();

    const int wave = tid >> 6, lane = tid & 63;
    const int quad = lane >> 4, m16 = lane & 15;
    const int rowl = wave * 16 + m16;
    const int swz = rowl & 7;
    s16x8 ah[8], al[8];
#pragma unroll
    for (int kf = 0; kf < 8; ++kf) {
        int pc = (kf * 4 + quad) ^ swz;
        ah[kf] = *(const s16x8*)(xH + rowl * 256 + pc * 8);
        al[kf] = *(const s16x8*)(xL + rowl * 256 + pc * 8);
    }
#pragma unroll
    for (int pt = 0; pt < 16; ++pt) {
        f32x4 acc = (f32x4){0.f, 0.f, 0.f, 0.f};
#pragma unroll
        for (int kf = 0; kf < 8; ++kf) {
            size_t idx = (size_t)(pt * 16 + m16) * DSIN + kf * 32 + quad * 8;
            s16x8 bh = *(const s16x8*)(WtH + idx);
            s16x8 bl = *(const s16x8*)(WtL + idx);
            acc = mfma16(ah[kf], bh, acc);
            acc = mfma16(al[kf], bh, acc);
            acc = mfma16(ah[kf], bl, acc);
        }
#pragma unroll
        for (int r = 0; r < 4; ++r)
            XQ[(size_t)(rowg0 + wave * 16 + quad * 4 + r) * PDIM + pt * 16 + m16] =
                f2bf(acc[r]);
    }
}

// ---------------- K3: fused attention, cooperative-S structure ----------------
// Block: 64 q x 256 p, 4 waves. Wave w: computes S-quarter (rows w*16..+16) via QK,
// exp/relu in C-layout -> bf16 Pe/Pr LDS; PV over p-slice [64w,64w+64) using all Pe/Pr.
// K: global_load_lds (XOR-swizzled source). V: registers from coalesced YVb.
__global__ __launch_bounds__(256, 2) void k_attn(const u16* __restrict__ XQ,
                                                 const u16* __restrict__ YK,
                                                 const u16* __restrict__ YVb,
                                                 float* __restrict__ accE,
                                                 float* __restrict__ accR,
                                                 float* __restrict__ lsum,
                                                 float* __restrict__ rsum,
                                                 int msPerSplit) {
    __shared__ u16 Kt[32 * 256];   // 32 keys x 256 d, XOR-swizzled chunks
    __shared__ u16 Pe[64 * 40];    // 64 q x 32 keys, pad->40 (2-way max)
    __shared__ u16 Pr[64 * 40];

    const int tid = threadIdx.x;
    const int wave = tid >> 6, lane = tid & 63;
    const int quad = lane >> 4, m16 = lane & 15;
    const int split = blockIdx.y;
    const int qbase = blockIdx.x * 64;
    const int key_begin = split * msPerSplit;
    const int iters = msPerSplit / BK;
    const int pslice = wave * 64;
    const int swz = m16 & 7;

    // Q A-frags for this wave's 16 S-rows
    s16x8 qf[8];
    const u16* qp = XQ + (size_t)(qbase + wave * 16 + m16) * DSIN;
#pragma unroll
    for (int kf = 0; kf < 8; ++kf)
        qf[kf] = *(const s16x8*)(qp + kf * 32 + quad * 8);

    f32x4 aE[4][4], aR[4][4];
#pragma unroll
    for (int g = 0; g < 4; ++g)
#pragma unroll
        for (int t = 0; t < 4; ++t) {
            aE[g][t] = (f32x4){0.f, 0.f, 0.f, 0.f};
            aR[g][t] = (f32x4){0.f, 0.f, 0.f, 0.f};
        }
    float lacc[4] = {0.f, 0.f, 0.f, 0.f}, racc[4] = {0.f, 0.f, 0.f, 0.f};

    // stage K tile for key0 via DMA; source chunk XOR-permuted so phys layout is swizzled
    auto stage = [&](int key0) {
#pragma unroll
        for (int c = 0; c < 4; ++c) {
            int l = (wave * 4 + c) * 64 + lane;   // phys chunk 0..1023
            int r = l >> 5;                        // key row 0..31
            int sc = (l & 31) ^ (r & 7);           // source chunk in row
            gload_lds16(YK + (size_t)(key0 + r) * DSIN + sc * 8,
                        Kt + (size_t)(wave * 4 + c) * 512);
        }
    };
    stage(key_begin);

    for (int it = 0; it < iters; ++it) {
        const int key0 = key_begin + it * BK;
        __syncthreads();   // Kt(it) visible (vmcnt0 + barrier)

        // QK: S-quarter rows wave*16+quad*4+r, keys m16 / 16+m16
        f32x4 s0 = (f32x4){0.f, 0.f, 0.f, 0.f};
        f32x4 s1 = (f32x4){0.f, 0.f, 0.f, 0.f};
#pragma unroll
        for (int kf = 0; kf < 8; ++kf) {
            int pc = (kf * 4 + quad) ^ swz;        // (16+m16)&7 == m16&7
            s16x8 b0 = *(const s16x8*)(Kt + m16 * 256 + pc * 8);
            s16x8 b1 = *(const s16x8*)(Kt + (16 + m16) * 256 + pc * 8);
            s0 = mfma16(qf[kf], b0, s0);
            s1 = mfma16(qf[kf], b1, s1);
        }
        // exp/relu in C-layout; per-lane partial row sums; bf16 -> Pe/Pr
#pragma unroll
        for (int r = 0; r < 4; ++r) {
            float e0 = __expf(s0[r]), e1 = __expf(s1[r]);
            float rl0 = fmaxf(s0[r], 0.f), rl1 = fmaxf(s1[r], 0.f);
            lacc[r] += e0 + e1;
            racc[r] += rl0 + rl1;
            int row = wave * 16 + quad * 4 + r;
            Pe[row * 40 + m16]      = f2bf(e0);
            Pe[row * 40 + 16 + m16] = f2bf(e1);
            Pr[row * 40 + m16]      = f2bf(rl0);
            Pr[row * 40 + 16 + m16] = f2bf(rl1);
        }
        __syncthreads();   // Pe/Pr visible; Kt free to overwrite

        // V-frags first (so their vmcnt wait doesn't drain the DMA below)
        s16x8 vf[4];
        const u16* vb = YVb + (size_t)((key0 >> 5) * PDIM) * 32;
#pragma unroll
        for (int t = 0; t < 4; ++t)
            vf[t] = *(const s16x8*)(vb + (size_t)(pslice + t * 16 + m16) * 32 + quad * 8);

        if (it + 1 < iters) stage(key0 + BK);  // async prefetch of next K tile

        // PV: dual path, V-frag reused 8x, Pe/Pr A-frags from LDS
#pragma unroll
        for (int g = 0; g < 4; ++g) {
            s16x8 pa = *(const s16x8*)(Pe + (g * 16 + m16) * 40 + quad * 8);
            s16x8 pb = *(const s16x8*)(Pr + (g * 16 + m16) * 40 + quad * 8);
#pragma unroll
            for (int t = 0; t < 4; ++t) {
                aE[g][t] = mfma16(pa, vf[t], aE[g][t]);
                aR[g][t] = mfma16(pb, vf[t], aR[g][t]);
            }
        }
    }

    // epilogue: partial O and row sums
    size_t ob = ((size_t)split * N_Q + qbase) * PDIM;
#pragma unroll
    for (int g = 0; g < 4; ++g)
#pragma unroll
        for (int t = 0; t < 4; ++t)
#pragma unroll
            for (int r = 0; r < 4; ++r) {
                size_t o = ob + (size_t)(g * 16 + quad * 4 + r) * PDIM + pslice + t * 16 + m16;
                accE[o] = aE[g][t][r];
                accR[o] = aR[g][t][r];
            }
#pragma unroll
    for (int r = 0; r < 4; ++r) {
        lacc[r] += __shfl_xor(lacc[r], 1);
        lacc[r] += __shfl_xor(lacc[r], 2);
        lacc[r] += __shfl_xor(lacc[r], 4);
        lacc[r] += __shfl_xor(lacc[r], 8);
        racc[r] += __shfl_xor(racc[r], 1);
        racc[r] += __shfl_xor(racc[r], 2);
        racc[r] += __shfl_xor(racc[r], 4);
        racc[r] += __shfl_xor(racc[r], 8);
    }
    if (m16 < 4) {
        float lv = (m16 == 0) ? lacc[0] : (m16 == 1) ? lacc[1] : (m16 == 2) ? lacc[2] : lacc[3];
        float rv = (m16 == 0) ? racc[0] : (m16 == 1) ? racc[1] : (m16 == 2) ? racc[2] : racc[3];
        int row = split * N_Q + qbase + wave * 16 + quad * 4 + m16;
        lsum[row] = lv;
        rsum[row] = rv;
    }
}

// ---------------- K4: combine splits + normalization (float4) ----------------
__global__ void k_comb(const float* __restrict__ accE, const float* __restrict__ accR,
                       const float* __restrict__ lsum, const float* __restrict__ rsum,
                       float* __restrict__ out, int nsplit) {
    int row = blockIdx.x * 4 + (threadIdx.x >> 6);
    size_t idx = (size_t)row * PDIM + (threadIdx.x & 63) * 4;
    const size_t NP = (size_t)N_Q * PDIM;
    float4 E = {0.f, 0.f, 0.f, 0.f}, R = {0.f, 0.f, 0.f, 0.f};
    float L = 0.f, Rs = 0.f;
    for (int s = 0; s < nsplit; ++s) {
        float4 e = *(const float4*)(accE + s * NP + idx);
        float4 r = *(const float4*)(accR + s * NP + idx);
        E.x += e.x; E.y += e.y; E.z += e.z; E.w += e.w;
        R.x += r.x; R.y += r.y; R.z += r.z; R.w += r.w;
        L  += lsum[(size_t)s * N_Q + row];
        Rs += rsum[(size_t)s * N_Q + row];
    }
    float invL = 1.f / L, invD = 1.f / (1.f + 0.1f * Rs);
    float4 o;
    o.x = (0.1f * R.x + E.x * invL) * invD;
    o.y = (0.1f * R.y + E.y * invL) * invD;
    o.z = (0.1f * R.z + E.z * invL) * invD;
    o.w = (0.1f * R.w + E.w * invL) * invD;
    *(float4*)(out + idx) = o;
}

extern "C" void kernel_launch(void* const* d_in, const int* in_sizes, int n_in,
                              void* d_out, int out_size, void* d_ws, size_t ws_size,
                              hipStream_t stream) {
    const float* x  = (const float*)d_in[0];
    const float* y  = (const float*)d_in[1];
    const float* Wq = (const float*)d_in[2];
    const float* Wk = (const float*)d_in[3];
    const float* Wv = (const float*)d_in[4];
    float* out = (float*)d_out;

    char* ws = (char*)d_ws;
    size_t off = 0;
    auto take = [&](size_t bytes) -> char* {
        char* p = ws + off;
        off += (bytes + 255) & ~(size_t)255;
        return p;
    };
    u16* XQ  = (u16*)take((size_t)N_Q * PDIM * 2);
    u16* WtH = (u16*)take((size_t)PDIM * DSIN * 2);
    u16* WtL = (u16*)take((size_t)PDIM * DSIN * 2);
    u16* YK  = (u16*)take((size_t)MCTX * PDIM * 2);
    u16* YVb = (u16*)take((size_t)MCTX * PDIM * 2);

    size_t perSplit = (size_t)N_Q * PDIM * 4 * 2 + (size_t)N_Q * 4 * 2 + 1024;
    int nsplit = (ws_size >= off + 2 * perSplit + 4096) ? 2 : 1;

    float* accE = (float*)take((size_t)nsplit * N_Q * PDIM * 4);
    float* accR = (float*)take((size_t)nsplit * N_Q * PDIM * 4);
    float* lsum = (float*)take((size_t)nsplit * N_Q * 4);
    float* rsum = (float*)take((size_t)nsplit * N_Q * 4);

    hipLaunchKernelGGL(k_wt,   dim3(PDIM),     dim3(DSIN), 0, stream, Wq, WtH, WtL);
    hipLaunchKernelGGL(k_ykv,  dim3(MCTX/32),  dim3(PDIM), 0, stream, y, Wk, Wv, YK, YVb);
    hipLaunchKernelGGL(k_xq,   dim3(N_Q/64),   dim3(256),  0, stream, x, WtH, WtL, XQ);
    hipLaunchKernelGGL(k_attn, dim3(N_Q/64, nsplit), dim3(256), 0, stream,
                       XQ, YK, YVb, accE, accR, lsum, rsum, MCTX / nsplit);
    hipLaunchKernelGGL(k_comb, dim3(N_Q/4),    dim3(256),  0, stream,
                       accE, accR, lsum, rsum, out, nsplit);
}